// Round 11
// baseline (384.529 us; speedup 1.0000x reference)
//
#include <hip/hip_runtime.h>

#define NP_   16384
#define NQ_   8192
#define NB_   2
#define K_    16
#define SPLIT 16
#define QPB   16          // queries per block
#define TPB   256
#define TILE  1024        // points per LDS tile
#define NTILES (NP_/TILE) // 16
#define JPT   (TILE/SPLIT) // 64 (tile-0 bootstrap path)
#define GPT   (TILE/64)    // 16 group-iterations per tile (main path)

#define IDX_OFF 0
#define RS_OFF  (NB_*NQ_*K_)        // 262144
#define RS_N    (NB_*NQ_+1)         // 16385
#define DST_OFF (RS_OFF + RS_N)     // 278529

__global__ __launch_bounds__(TPB, 4) void knn_kernel(const float* __restrict__ pts,
                                                     const float* __restrict__ qrs,
                                                     float* __restrict__ out)
{
    // Validated exact-match formula (R6):
    //   sq, sp : forward sum, separate mul/add rounds
    //   ip     : forward FMA chain  fma(z,qz, fma(y,qy, round(x*qx)))
    //   d      : fmaf(-2, ip, sq+sp)   (== (sq+sp)-2*ip bit-exactly)
    #pragma clang fp contract(off)

    __shared__ union SmemU {
        float4 tile[TILE];          // 16KB (scan phase)
        float2 merge[K_][TPB];      // 32KB (merge phase)
    } sm;

    const int tid  = threadIdx.x;
    const int lane = tid & 63;
    const int s    = tid & (SPLIT - 1);
    const int gq   = blockIdx.x * QPB + (tid >> 4);  // own query (list owner)
    const int batch = gq >> 13;
    const int gofs  = batch * NP_;
    const float* pb = pts + (size_t)gofs * 3;

    // own query coords (drain + tile-0 path)
    const float qox = qrs[gq*3+0], qoy = qrs[gq*3+1], qoz = qrs[gq*3+2];
    const float sqo = qox*qox + qoy*qoy + qoz*qoz;   // fwd, no FMA

    // the wave's 4 queries (verdict evaluation)
    const int qbase = blockIdx.x * QPB + (tid >> 6) * 4;
    float q4x[4], q4y[4], q4z[4], sq4[4];
    #pragma unroll
    for (int qi = 0; qi < 4; ++qi) {
        q4x[qi] = qrs[(qbase+qi)*3+0];
        q4y[qi] = qrs[(qbase+qi)*3+1];
        q4z[qi] = qrs[(qbase+qi)*3+2];
        sq4[qi] = q4x[qi]*q4x[qi] + q4y[qi]*q4y[qi] + q4z[qi]*q4z[qi];
    }

    const float INF = __int_as_float(0x7f800000);
    float ad[K_]; int ai[K_];
    #pragma unroll
    for (int i = 0; i < K_; ++i) { ad[i] = INF; ai[i] = 0x7fffffff; }

    const unsigned long long slicemask = 0x0001000100010001ull << s;

    // exact distance: point pp vs OWN query (identical chain everywhere)
    auto dOwn = [&](float4 pp) {
        float ip = fmaf(pp.z, qoz, fmaf(pp.y, qoy, __fmul_rn(pp.x, qox)));
        return fmaf(-2.0f, ip, sqo + pp.w);
    };

    auto insert1 = [&](float d, int gi) {
        if (d < ad[K_-1]) {                     // strict: stable on ties
            ad[K_-1] = d; ai[K_-1] = gi;
            #pragma unroll
            for (int i = K_-1; i > 0; --i) {
                bool sw = ad[i] < ad[i-1];
                float td = ad[i-1]; int ti = ai[i-1];
                ad[i-1] = sw ? ad[i] : td;  ai[i-1] = sw ? ai[i] : ti;
                ad[i]   = sw ? td   : ad[i]; ai[i]  = sw ? ti   : ai[i];
            }
        }
    };

    auto qmin16 = [&](float w) {               // shared per-query upper bound
        #pragma unroll
        for (int off = 8; off >= 1; off >>= 1)
            w = fminf(w, __shfl_xor(w, off, SPLIT));
        return w;
    };

    float thresh = INF;          // own-query threshold
    float th[4];                 // wave's 4 query thresholds (broadcast)

    for (int t = 0; t < NTILES; ++t) {
        __syncthreads();
        #pragma unroll
        for (int k = 0; k < TILE/TPB; ++k) {
            int lp = tid + k*TPB;
            int gp = t*TILE + lp;
            float x = pb[gp*3+0], y = pb[gp*3+1], z = pb[gp*3+2];
            float sp = x*x + y*y + z*z;         // fwd, no FMA
            sm.tile[lp] = make_float4(x, y, z, sp);
        }
        __syncthreads();

        if (t == 0) {
            // ---- bootstrap (R10 path, own query only) ----
            for (int j = 0; j < K_; ++j)
                insert1(dOwn(sm.tile[j*SPLIT + s]), j*SPLIT + s);
            thresh = qmin16(ad[K_-1]);
            unsigned long long mask = 0ull;
            #pragma unroll 8
            for (int j = K_; j < JPT; ++j) {
                bool pass = dOwn(sm.tile[j*SPLIT + s]) <= thresh;
                if (__any(pass)) { if (pass) mask |= (1ull << j); }
            }
            while (mask) {
                int j = __ffsll(mask) - 1;  mask &= mask - 1;
                insert1(dOwn(sm.tile[j*SPLIT + s]), j*SPLIT + s);
            }
        } else {
            // ---- main path: 1 point read -> 4 query verdicts -> ballot ----
            #pragma unroll 2
            for (int g = 0; g < GPT; ++g) {
                float4 p = sm.tile[g*64 + lane];
                float spw0 = sq4[0] + p.w, spw1 = sq4[1] + p.w;
                float spw2 = sq4[2] + p.w, spw3 = sq4[3] + p.w;
                float ip0 = fmaf(p.z, q4z[0], fmaf(p.y, q4y[0], __fmul_rn(p.x, q4x[0])));
                float ip1 = fmaf(p.z, q4z[1], fmaf(p.y, q4y[1], __fmul_rn(p.x, q4x[1])));
                float ip2 = fmaf(p.z, q4z[2], fmaf(p.y, q4y[2], __fmul_rn(p.x, q4x[2])));
                float ip3 = fmaf(p.z, q4z[3], fmaf(p.y, q4y[3], __fmul_rn(p.x, q4x[3])));
                float d0 = fmaf(-2.0f, ip0, spw0);
                float d1 = fmaf(-2.0f, ip1, spw1);
                float d2 = fmaf(-2.0f, ip2, spw2);
                float d3 = fmaf(-2.0f, ip3, spw3);
                unsigned long long m0 = __ballot(d0 <= th[0]);
                unsigned long long m1 = __ballot(d1 <= th[1]);
                unsigned long long m2 = __ballot(d2 <= th[2]);
                unsigned long long m3 = __ballot(d3 <= th[3]);
                if (m0 | m1 | m2 | m3) {        // uniform -> scalar skip
                    int qo = (lane >> 4);
                    unsigned long long mo = (qo == 0) ? m0 : (qo == 1) ? m1
                                          : (qo == 2) ? m2 : m3;
                    mo &= slicemask;            // bits with pid%16 == s
                    while (mo) {                // ascending pid => stable
                        int b = __ffsll(mo) - 1;  mo &= mo - 1;
                        int pid = g*64 + b;
                        insert1(dOwn(sm.tile[pid]), t*TILE + pid);
                    }
                }
            }
        }

        // ---- tile end: tighten + broadcast thresholds ----
        thresh = qmin16(ad[K_-1]);
        #pragma unroll
        for (int qi = 0; qi < 4; ++qi)
            th[qi] = __shfl(thresh, qi * 16, 64);
    }

    __syncthreads();      // scan done; reuse LDS for merge lists
    #pragma unroll
    for (int m = 0; m < K_; ++m)
        sm.merge[m][tid] = make_float2(ad[m], __int_as_float(ai[m]));
    __syncthreads();

    // 16-way merge of 16 sorted lists per query via width-16 shfl min-reduce
    int pos = 1;
    float hd = ad[0]; int hi = ai[0];
    float rd = 0.0f;  int ri = 0;
    #pragma unroll
    for (int r = 0; r < K_; ++r) {
        float bd = hd; int bi = hi; int bl = s;
        #pragma unroll
        for (int off = 8; off >= 1; off >>= 1) {
            float od = __shfl_xor(bd, off, SPLIT);
            int   oi = __shfl_xor(bi, off, SPLIT);
            int   ol = __shfl_xor(bl, off, SPLIT);
            bool take = (od < bd) || (od == bd && oi < bi);   // lexicographic: stable
            bd = take ? od : bd; bi = take ? oi : bi; bl = take ? ol : bl;
        }
        if (r == s) { rd = bd; ri = bi; }     // lane s keeps rank-s result
        if (bl == s) {                        // winner advances its head
            if (pos < K_) { float2 e = sm.merge[pos][tid]; hd = e.x; hi = __float_as_int(e.y); ++pos; }
            else { hd = __int_as_float(0x7f800000); hi = 0x7fffffff; }
        }
    }

    // coalesced output: lane s writes rank-s neighbor of its query
    out[IDX_OFF + gq*K_ + s] = (float)(ri + gofs);
    out[DST_OFF + gq*K_ + s] = fmaxf(rd, 0.0f);

    // row_splits = arange(16385) * 16, written as float (exact)
    int gt = blockIdx.x * TPB + tid;
    if (gt < RS_N) out[RS_OFF + gt] = (float)(gt * K_);
}

extern "C" void kernel_launch(void* const* d_in, const int* in_sizes, int n_in,
                              void* d_out, int out_size, void* d_ws, size_t ws_size,
                              hipStream_t stream)
{
    const float* pts = (const float*)d_in[0];
    const float* qrs = (const float*)d_in[1];
    float* out = (float*)d_out;
    (void)in_sizes; (void)n_in; (void)out_size; (void)d_ws; (void)ws_size;

    dim3 grid(NB_ * NQ_ / QPB);   // 1024 blocks
    dim3 block(TPB);              // 256 threads
    knn_kernel<<<grid, block, 0, stream>>>(pts, qrs, out);
}